// Round 4
// baseline (348.618 us; speedup 1.0000x reference)
//
#include <hip/hip_runtime.h>

typedef unsigned int u32;
typedef _Float16 v2h __attribute__((ext_vector_type(2)));
typedef __fp16   v2fp __attribute__((ext_vector_type(2)));

#define E_TOT 160000
#define TPB   128
#define NTILE 625          // 160000 / 256 edges per block (2 edges per thread)
#define NBLK  (NTILE * 2)  // x2 classes
#define HSTR  51           // arena stride per thread (u32), odd -> conflict-free
// per-edge arena (u32): [0..16] = hp pairs (slot16 = const (1,0) bias selector)
//                       [17..24] = t01 stash as raw f32 bits (class B)
// two edges per thread: H0 = AR + tid*51, H1 = H0 + 25  (50 used of 51)
// ws (u32, f16-pairs): [p(0,0):0..1920) [p(1,0):1920..3840) [p(0,1):3840..5760) [p(1,1):5760..9856)
// per p<3 pair: W1p[9][32]@+0 | W2p[17][32]@+288 | W3p[34 rows][32 cp]@+832   (rows 32=b3,33=0)
// p3 pair:      W1p@+0 | W2p@+288 | W3p[17 mp][192 c]@+832                     (mp16=(b3,0))
// Weights read DIRECTLY from global ws with wave-uniform addresses -> s_load
// into SGPRs (one fetch per wave, scalar pipe). Each thread processes TWO
// edges (e, e+128) so every uniform weight fetch feeds 2x the FDOT2 work.
// launch_bounds(128,2): VGPR cap 256 — R2 proved the interleaved 2-edge
// class-B live set fits ~124 VGPR at this cap with ZERO scratch; cap 168 (R3)
// caused 75 MB of spill traffic each way.

#if __has_builtin(__builtin_amdgcn_fdot2)
__device__ __forceinline__ float FDOT2(v2h a, v2h b, float c){
  return __builtin_amdgcn_fdot2(a, b, c, false);
}
#else
__device__ __forceinline__ float FDOT2(v2h a, v2h b, float c){
  return fmaf((float)a[0], (float)b[0], fmaf((float)a[1], (float)b[1], c));
}
#endif

__device__ __forceinline__ u32 pkh(float a, float b){
  union { v2fp h; u32 x; } u;
  u.h = __builtin_amdgcn_cvt_pkrtz(a, b);
  return u.x;
}
__device__ __forceinline__ v2h asvh(u32 x){
  union { u32 x; v2h h; } u; u.x = x; return u.h;
}

struct WPtrs { const float* p[24]; };  // pair order (0,0),(1,0),(0,1),(1,1) x {w1,b1,w2,b2,w3,b3}

__global__ __launch_bounds__(256) void prep_kernel(WPtrs S, u32* __restrict__ ws)
{
  const int t = blockIdx.x * 256 + threadIdx.x;
  if (t >= 9856) return;
  int pair, rel;
  if (t < 5760){ pair = t / 1920; rel = t % 1920; }
  else         { pair = 3;        rel = t - 5760; }
  const float* __restrict__ w1 = S.p[pair*6+0];
  const float* __restrict__ b1 = S.p[pair*6+1];
  const float* __restrict__ w2 = S.p[pair*6+2];
  const float* __restrict__ b2 = S.p[pair*6+3];
  const float* __restrict__ w3 = S.p[pair*6+4];
  const float* __restrict__ b3 = S.p[pair*6+5];
  float a, b;
  if (rel < 288){                       // W1p: k-pairs, row 8 pairs (w1[16], b1)
    int kp = rel >> 5, m = rel & 31;
    a = w1[2*kp*32 + m];
    b = (2*kp+1 < 17) ? w1[(2*kp+1)*32 + m] : b1[m];
  } else if (rel < 832){                // W2p: k-pairs, row 16 = (b2, 0)
    int j = rel - 288, kp = j >> 5, m = j & 31;
    if (kp < 16){ a = w2[2*kp*32 + m]; b = w2[(2*kp+1)*32 + m]; }
    else        { a = b2[m];           b = 0.f; }
  } else if (pair < 3){                 // W3p34: c-pairs, rows 32=b3,33=0
    int j = rel - 832, r = j >> 5, cp = j & 31;
    if      (r < 32){ a = w3[r*64 + 2*cp]; b = w3[r*64 + 2*cp + 1]; }
    else if (r ==32){ a = b3[2*cp];        b = b3[2*cp + 1]; }
    else            { a = 0.f;             b = 0.f; }
  } else {                              // W3p17: m-pairs, mp16 = (b3, 0)
    int j = rel - 832, mp = j / 192, c = j % 192;
    if (mp < 16){ a = w3[2*mp*192 + c]; b = w3[(2*mp+1)*192 + c]; }
    else        { a = b3[c];            b = 0.f; }
  }
  ws[t] = pkh(a, b);
}

// radial MLP for two edges sharing uniform s_load weight fetches.
// xp in VGPRs (layer1 fully unrolled); h pairs live in LDS arenas H0/H1.
__device__ __forceinline__ void mlp2(const u32* __restrict__ W, int pb,
                                     const u32 (&xp0)[9], const u32 (&xp1)[9],
                                     u32* __restrict__ H0, u32* __restrict__ H1)
{
  float g[64];
  #pragma unroll
  for (int m = 0; m < 64; ++m) g[m] = 0.f;
  #pragma unroll
  for (int kp = 0; kp < 9; ++kp){
    v2h x0 = asvh(xp0[kp]);
    v2h x1 = asvh(xp1[kp]);
    const uint4* __restrict__ r4 = (const uint4*)(W + pb + kp*32);
    #pragma unroll
    for (int j = 0; j < 8; ++j){
      uint4 w = r4[j];                               // s_load_dwordx4 (uniform)
      g[4*j+0]    = FDOT2(asvh(w.x), x0, g[4*j+0]);
      g[4*j+1]    = FDOT2(asvh(w.y), x0, g[4*j+1]);
      g[4*j+2]    = FDOT2(asvh(w.z), x0, g[4*j+2]);
      g[4*j+3]    = FDOT2(asvh(w.w), x0, g[4*j+3]);
      g[32+4*j+0] = FDOT2(asvh(w.x), x1, g[32+4*j+0]);
      g[32+4*j+1] = FDOT2(asvh(w.y), x1, g[32+4*j+1]);
      g[32+4*j+2] = FDOT2(asvh(w.z), x1, g[32+4*j+2]);
      g[32+4*j+3] = FDOT2(asvh(w.w), x1, g[32+4*j+3]);
    }
  }
  #pragma unroll
  for (int j = 0; j < 16; ++j){
    H0[j] = pkh(fmaxf(g[2*j], 0.f),    fmaxf(g[2*j+1], 0.f));
    H1[j] = pkh(fmaxf(g[32+2*j], 0.f), fmaxf(g[32+2*j+1], 0.f));
  }
  float g2[64];
  #pragma unroll
  for (int m = 0; m < 64; ++m) g2[m] = 0.f;
  #pragma unroll 2
  for (int kp = 0; kp < 17; ++kp){                   // kp=16 reads H[16]=(1,0) -> +b2
    v2h x0 = asvh(H0[kp]);
    v2h x1 = asvh(H1[kp]);
    const uint4* __restrict__ r4 = (const uint4*)(W + pb + 288 + kp*32);
    #pragma unroll
    for (int j = 0; j < 8; ++j){
      uint4 w = r4[j];
      g2[4*j+0]    = FDOT2(asvh(w.x), x0, g2[4*j+0]);
      g2[4*j+1]    = FDOT2(asvh(w.y), x0, g2[4*j+1]);
      g2[4*j+2]    = FDOT2(asvh(w.z), x0, g2[4*j+2]);
      g2[4*j+3]    = FDOT2(asvh(w.w), x0, g2[4*j+3]);
      g2[32+4*j+0] = FDOT2(asvh(w.x), x1, g2[32+4*j+0]);
      g2[32+4*j+1] = FDOT2(asvh(w.y), x1, g2[32+4*j+1]);
      g2[32+4*j+2] = FDOT2(asvh(w.z), x1, g2[32+4*j+2]);
      g2[32+4*j+3] = FDOT2(asvh(w.w), x1, g2[32+4*j+3]);
    }
  }
  #pragma unroll
  for (int j = 0; j < 16; ++j){
    H0[j] = pkh(fmaxf(g2[2*j], 0.f),    fmaxf(g2[2*j+1], 0.f));
    H1[j] = pkh(fmaxf(g2[32+2*j], 0.f), fmaxf(g2[32+2*j+1], 0.f));
  }
}

// layer3, 64 cols (c-paired), two edges: acc_e[o] = sum_rows h_r,e * (w3row . v_e)
__device__ __forceinline__ void l3a2(const u32* __restrict__ W, int wb,
                                     const u32* __restrict__ H0, const u32* __restrict__ H1,
                                     const u32 (&vpA)[4], const u32 (&vpB)[4],
                                     float (&acc0)[8], float (&acc1)[8])
{
  #pragma unroll
  for (int o = 0; o < 8; ++o){ acc0[o] = 0.f; acc1[o] = 0.f; }
  #pragma unroll 1
  for (int mp = 0; mp < 17; ++mp){
    v2h hp0 = asvh(H0[mp]);
    v2h hp1 = asvh(H1[mp]);
    float h00 = (float)hp0[0], h01 = (float)hp0[1];
    float h10 = (float)hp1[0], h11 = (float)hp1[1];
    const uint4* __restrict__ rA = (const uint4*)(W + wb + (2*mp)*32);
    const uint4* __restrict__ rB = rA + 8;
    #pragma unroll
    for (int o = 0; o < 8; ++o){
      uint4 wa  = rA[o];                             // s_load (uniform)
      uint4 wb2 = rB[o];
      float tA0 = 0.f, tB0 = 0.f, tA1 = 0.f, tB1 = 0.f;
      tA0 = FDOT2(asvh(wa.x),  asvh(vpA[0]), tA0);
      tA0 = FDOT2(asvh(wa.y),  asvh(vpA[1]), tA0);
      tA0 = FDOT2(asvh(wa.z),  asvh(vpA[2]), tA0);
      tA0 = FDOT2(asvh(wa.w),  asvh(vpA[3]), tA0);
      tB0 = FDOT2(asvh(wb2.x), asvh(vpA[0]), tB0);
      tB0 = FDOT2(asvh(wb2.y), asvh(vpA[1]), tB0);
      tB0 = FDOT2(asvh(wb2.z), asvh(vpA[2]), tB0);
      tB0 = FDOT2(asvh(wb2.w), asvh(vpA[3]), tB0);
      tA1 = FDOT2(asvh(wa.x),  asvh(vpB[0]), tA1);
      tA1 = FDOT2(asvh(wa.y),  asvh(vpB[1]), tA1);
      tA1 = FDOT2(asvh(wa.z),  asvh(vpB[2]), tA1);
      tA1 = FDOT2(asvh(wa.w),  asvh(vpB[3]), tA1);
      tB1 = FDOT2(asvh(wb2.x), asvh(vpB[0]), tB1);
      tB1 = FDOT2(asvh(wb2.y), asvh(vpB[1]), tB1);
      tB1 = FDOT2(asvh(wb2.z), asvh(vpB[2]), tB1);
      tB1 = FDOT2(asvh(wb2.w), asvh(vpB[3]), tB1);
      acc0[o] = fmaf(h00, tA0, fmaf(h01, tB0, acc0[o]));
      acc1[o] = fmaf(h10, tA1, fmaf(h11, tB1, acc1[o]));
    }
  }
}

// class-B epilogue for one edge, one o: D + Bv contraction + store
__device__ __forceinline__ void dout(const float (&a24)[24], const float (&s1)[24],
                                     const float (&Bv)[27], const float (&B01)[3],
                                     float t01o, float* __restrict__ o1, int o)
{
  float D[9];                           // D[q,f] = sum_i R[o,i,f]*s1[i,q]
  #pragma unroll
  for (int q = 0; q < 3; ++q){
    #pragma unroll
    for (int f = 0; f < 3; ++f){
      float t = 0.f;
      #pragma unroll
      for (int i = 0; i < 8; ++i) t = fmaf(a24[i*3+f], s1[i*3+q], t);
      D[q*3+f] = t;
    }
  }
  #pragma unroll
  for (int p = 0; p < 3; ++p){
    float t = t01o * B01[p];
    #pragma unroll
    for (int q = 0; q < 3; ++q){
      #pragma unroll
      for (int f = 0; f < 3; ++f)
        t = fmaf(Bv[p*9 + q*3 + f], D[q*3+f], t);
    }
    o1[o*3 + p] = t;
  }
}

__device__ __forceinline__ void load_xp(const float* __restrict__ wE,
                                        const float* __restrict__ radial,
                                        int e, u32 (&xp)[9])
{
  const float4* wp = (const float4*)(wE + (size_t)e * 16);
  float4 a = wp[0], b = wp[1], c = wp[2], d = wp[3];
  xp[0] = pkh(a.x, a.y); xp[1] = pkh(a.z, a.w);
  xp[2] = pkh(b.x, b.y); xp[3] = pkh(b.z, b.w);
  xp[4] = pkh(c.x, c.y); xp[5] = pkh(c.z, c.w);
  xp[6] = pkh(d.x, d.y); xp[7] = pkh(d.z, d.w);
  xp[8] = pkh(radial[e], 1.0f);         // pairs with (w1[16], b1) row
}

__global__ __launch_bounds__(TPB, 2) void edge_kernel(
    const float* __restrict__ feat0, const float* __restrict__ feat1,
    const float* __restrict__ wE,    const float* __restrict__ radial,
    const float* __restrict__ b00,   const float* __restrict__ b01,
    const float* __restrict__ b10,   const float* __restrict__ b11,
    const int* __restrict__ src_idx, const u32* __restrict__ ws,
    float* __restrict__ out)
{
  __shared__ u32 AR[TPB * HSTR];           // per-thread 2-edge arenas, 26.1 KB
  const int tid = threadIdx.x;
  const int cls = blockIdx.x & 1;
  const int e0  = (blockIdx.x >> 1) * 256 + tid;
  const int e1  = e0 + 128;                // always < E_TOT (625*256 = 160000)
  u32* H0 = AR + tid * HSTR;               // edge0 arena (25 used)
  u32* H1 = H0 + 25;                       // edge1 arena

  u32 xp0[9], xp1[9];
  load_xp(wE, radial, e0, xp0);
  load_xp(wE, radial, e1, xp1);
  const int idx0 = src_idx[e0];
  const int idx1 = src_idx[e1];
  u32 vp00[4], vp01[4];
  {
    const float4* f0 = (const float4*)(feat0 + (size_t)idx0 * 8);
    float4 a = f0[0], b = f0[1];
    vp00[0] = pkh(a.x, a.y); vp00[1] = pkh(a.z, a.w);
    vp00[2] = pkh(b.x, b.y); vp00[3] = pkh(b.z, b.w);
    const float4* f1 = (const float4*)(feat0 + (size_t)idx1 * 8);
    float4 c = f1[0], d = f1[1];
    vp01[0] = pkh(c.x, c.y); vp01[1] = pkh(c.z, c.w);
    vp01[2] = pkh(d.x, d.y); vp01[3] = pkh(d.z, d.w);
  }
  H0[16] = 0x00003C00u;                    // (1,0): bias selector
  H1[16] = 0x00003C00u;
  // no __syncthreads anywhere: arenas are strictly per-thread

  if (cls == 0){
    // ================= class A: pairs (0,0) + (1,0) -> out0 =================
    const float bB0 = b00[e0], bB1 = b00[e1];
    float B10a[3], B10b[3];
    #pragma unroll
    for (int q = 0; q < 3; ++q){ B10a[q] = b10[(size_t)e0*3 + q]; B10b[q] = b10[(size_t)e1*3 + q]; }
    u32 vp20[4], vp21[4];
    {
      float s1[24], Uv[8];
      const float4* f1 = (const float4*)(feat1 + (size_t)idx0 * 24);
      #pragma unroll
      for (int j = 0; j < 6; ++j){
        float4 v = f1[j];
        s1[4*j+0]=v.x; s1[4*j+1]=v.y; s1[4*j+2]=v.z; s1[4*j+3]=v.w;
      }
      #pragma unroll
      for (int i = 0; i < 8; ++i)
        Uv[i] = fmaf(B10a[0], s1[3*i+0], fmaf(B10a[1], s1[3*i+1], B10a[2]*s1[3*i+2]));
      #pragma unroll
      for (int j = 0; j < 4; ++j) vp20[j] = pkh(Uv[2*j], Uv[2*j+1]);
      const float4* f2 = (const float4*)(feat1 + (size_t)idx1 * 24);
      #pragma unroll
      for (int j = 0; j < 6; ++j){
        float4 v = f2[j];
        s1[4*j+0]=v.x; s1[4*j+1]=v.y; s1[4*j+2]=v.z; s1[4*j+3]=v.w;
      }
      #pragma unroll
      for (int i = 0; i < 8; ++i)
        Uv[i] = fmaf(B10b[0], s1[3*i+0], fmaf(B10b[1], s1[3*i+1], B10b[2]*s1[3*i+2]));
      #pragma unroll
      for (int j = 0; j < 4; ++j) vp21[j] = pkh(Uv[2*j], Uv[2*j+1]);
    }
    float msg00[8], msg01[8], acc0[8], acc1[8];
    mlp2(ws, 0, xp0, xp1, H0, H1);                 // pair (0,0)
    l3a2(ws, 832, H0, H1, vp00, vp01, acc0, acc1);
    #pragma unroll
    for (int o = 0; o < 8; ++o){ msg00[o] = acc0[o] * bB0; msg01[o] = acc1[o] * bB1; }
    mlp2(ws, 1920, xp0, xp1, H0, H1);              // pair (1,0)
    l3a2(ws, 1920 + 832, H0, H1, vp20, vp21, acc0, acc1);
    #pragma unroll
    for (int o = 0; o < 8; ++o){ msg00[o] += acc0[o]; msg01[o] += acc1[o]; }
    float* oA = out + (size_t)e0 * 8;
    ((float4*)oA)[0] = make_float4(msg00[0], msg00[1], msg00[2], msg00[3]);
    ((float4*)oA)[1] = make_float4(msg00[4], msg00[5], msg00[6], msg00[7]);
    float* oB = out + (size_t)e1 * 8;
    ((float4*)oB)[0] = make_float4(msg01[0], msg01[1], msg01[2], msg01[3]);
    ((float4*)oB)[1] = make_float4(msg01[4], msg01[5], msg01[6], msg01[7]);
  } else {
    // ================= class B: pairs (0,1) + (1,1) -> out1 =================
    float B01a[3], B01b[3];
    #pragma unroll
    for (int q = 0; q < 3; ++q){ B01a[q] = b01[(size_t)e0*3 + q]; B01b[q] = b01[(size_t)e1*3 + q]; }
    float t010[8], t011[8];
    mlp2(ws, 3840, xp0, xp1, H0, H1);              // pair (0,1)
    l3a2(ws, 3840 + 832, H0, H1, vp00, vp01, t010, t011);
    #pragma unroll
    for (int o = 0; o < 8; ++o){                   // stash t01 exact (f32 bits)
      H0[17 + o] = __float_as_uint(t010[o]);
      H1[17 + o] = __float_as_uint(t011[o]);
    }
    // issue s1 / Bv global loads BEFORE the (1,1) mlp2 so their latency hides
    // under ~2000 cycles of MLP compute (cap-256 gives room to keep them live)
    float s10[24], s11[24];
    {
      const float4* f1 = (const float4*)(feat1 + (size_t)idx0 * 24);
      #pragma unroll
      for (int j = 0; j < 6; ++j){
        float4 v = f1[j];
        s10[4*j+0]=v.x; s10[4*j+1]=v.y; s10[4*j+2]=v.z; s10[4*j+3]=v.w;
      }
      const float4* f2 = (const float4*)(feat1 + (size_t)idx1 * 24);
      #pragma unroll
      for (int j = 0; j < 6; ++j){
        float4 v = f2[j];
        s11[4*j+0]=v.x; s11[4*j+1]=v.y; s11[4*j+2]=v.z; s11[4*j+3]=v.w;
      }
    }
    float Bv0[27], Bv1[27];
    {
      const float* __restrict__ bp0 = b11 + (size_t)e0 * 27;
      const float* __restrict__ bp1 = b11 + (size_t)e1 * 27;
      #pragma unroll
      for (int j = 0; j < 27; ++j){ Bv0[j] = bp0[j]; Bv1[j] = bp1[j]; }
    }
    mlp2(ws, 5760, xp0, xp1, H0, H1);              // pair (1,1)
    float* o1a = out + (size_t)E_TOT * 8 + (size_t)e0 * 24;
    float* o1b = out + (size_t)E_TOT * 8 + (size_t)e1 * 24;
    #pragma unroll 1
    for (int o = 0; o < 8; ++o){
      float a0[24], a1[24];
      #pragma unroll
      for (int c = 0; c < 24; ++c){ a0[c] = 0.f; a1[c] = 0.f; }
      #pragma unroll 2
      for (int mp = 0; mp < 17; ++mp){             // mp16 row = (b3,0) with hp=(1,0)
        v2h hp0 = asvh(H0[mp]);
        v2h hp1 = asvh(H1[mp]);
        const uint4* __restrict__ seg = (const uint4*)(ws + 5760 + 832 + mp*192 + o*24);
        #pragma unroll
        for (int j4 = 0; j4 < 6; ++j4){
          uint4 w = seg[j4];                       // s_load (uniform)
          a0[4*j4+0] = FDOT2(asvh(w.x), hp0, a0[4*j4+0]);
          a0[4*j4+1] = FDOT2(asvh(w.y), hp0, a0[4*j4+1]);
          a0[4*j4+2] = FDOT2(asvh(w.z), hp0, a0[4*j4+2]);
          a0[4*j4+3] = FDOT2(asvh(w.w), hp0, a0[4*j4+3]);
          a1[4*j4+0] = FDOT2(asvh(w.x), hp1, a1[4*j4+0]);
          a1[4*j4+1] = FDOT2(asvh(w.y), hp1, a1[4*j4+1]);
          a1[4*j4+2] = FDOT2(asvh(w.z), hp1, a1[4*j4+2]);
          a1[4*j4+3] = FDOT2(asvh(w.w), hp1, a1[4*j4+3]);
        }
      }
      float t0 = __uint_as_float(H0[17 + o]);
      float t1 = __uint_as_float(H1[17 + o]);
      dout(a0, s10, Bv0, B01a, t0, o1a, o);
      dout(a1, s11, Bv1, B01b, t1, o1b, o);
    }
  }
}

extern "C" void kernel_launch(void* const* d_in, const int* in_sizes, int n_in,
                              void* d_out, int out_size, void* d_ws, size_t ws_size,
                              hipStream_t stream)
{
  const float* feat0 = (const float*)d_in[0];
  const float* feat1 = (const float*)d_in[1];
  const float* wE    = (const float*)d_in[2];
  const float* rad   = (const float*)d_in[3];
  const float* b00   = (const float*)d_in[4];
  const float* b01   = (const float*)d_in[11];
  const float* b10   = (const float*)d_in[18];
  const float* b11   = (const float*)d_in[25];
  const int* sidx    = (const int*)d_in[32];
  u32* ws            = (u32*)d_ws;

  // ws pair order: (0,0), (1,0), (0,1), (1,1)  -> d_in weight bases 5, 19, 12, 26
  const int base[4] = {5, 19, 12, 26};
  WPtrs S;
  for (int p = 0; p < 4; ++p)
    for (int k = 0; k < 6; ++k)
      S.p[p*6 + k] = (const float*)d_in[base[p] + k];

  prep_kernel<<<39, 256, 0, stream>>>(S, ws);
  edge_kernel<<<NBLK, TPB, 0, stream>>>(feat0, feat1, wE, rad, b00, b01, b10, b11,
                                        sidx, ws, (float*)d_out);
}

// Round 5
// 300.828 us; speedup vs baseline: 1.1589x; 1.1589x over previous
//
#include <hip/hip_runtime.h>

typedef unsigned int u32;
typedef _Float16 v2h __attribute__((ext_vector_type(2)));
typedef __fp16   v2fp __attribute__((ext_vector_type(2)));

#define E_TOT 160000
#define TPB   256
#define NBLK  1250        // (E/256)=625 tiles x 2 classes
#define ARENA 27          // u32/thread: xp[0..8] | hp[9..25] (17) | pad
// ws (u32, f16-pairs): [p(0,0):0..1920) [p(1,0):1920..3840) [p(0,1):3840..5760) [p(1,1):5760..9856)
// per p<3 pair: W1p[9][32]@+0 | W2p[17][32]@+288 | W3p[34 rows][32 cp]@+832   (rows 32=b3,33=0)
// p3 pair:      W1p@+0 | W2p@+288 | W3p[17 mp][192 c]@+832                     (mp16=(b3,0))
// Weights read DIRECTLY from global ws with wave-uniform addresses -> s_load
// into SGPRs (one fetch per wave, scalar pipe), v_dot2 takes SGPR src.
// R5: weight-sweep loops UNROLLED (x2/x3) so 2-3 row batches of s_loads are in
// flight per lgkmcnt wait (R1's unroll-1 serialized issue->drain->consume, 41% VALU).
// launch_bounds(256,2): VGPR cap 256 kills R1's residual ~30MB spill.
// s1/Bv loads NOT hoisted across mlp (R4 lesson: that collision forces spills).

#if __has_builtin(__builtin_amdgcn_fdot2)
__device__ __forceinline__ float FDOT2(v2h a, v2h b, float c){
  return __builtin_amdgcn_fdot2(a, b, c, false);
}
#else
__device__ __forceinline__ float FDOT2(v2h a, v2h b, float c){
  return fmaf((float)a[0], (float)b[0], fmaf((float)a[1], (float)b[1], c));
}
#endif

__device__ __forceinline__ u32 pkh(float a, float b){
  union { v2fp h; u32 x; } u;
  u.h = __builtin_amdgcn_cvt_pkrtz(a, b);
  return u.x;
}
__device__ __forceinline__ v2h asvh(u32 x){
  union { u32 x; v2h h; } u; u.x = x; return u.h;
}

struct WPtrs { const float* p[24]; };  // pair order (0,0),(1,0),(0,1),(1,1) x {w1,b1,w2,b2,w3,b3}

__global__ __launch_bounds__(256) void prep_kernel(WPtrs S, u32* __restrict__ ws)
{
  const int t = blockIdx.x * 256 + threadIdx.x;
  if (t >= 9856) return;
  int pair, rel;
  if (t < 5760){ pair = t / 1920; rel = t % 1920; }
  else         { pair = 3;        rel = t - 5760; }
  const float* __restrict__ w1 = S.p[pair*6+0];
  const float* __restrict__ b1 = S.p[pair*6+1];
  const float* __restrict__ w2 = S.p[pair*6+2];
  const float* __restrict__ b2 = S.p[pair*6+3];
  const float* __restrict__ w3 = S.p[pair*6+4];
  const float* __restrict__ b3 = S.p[pair*6+5];
  float a, b;
  if (rel < 288){                       // W1p: k-pairs, row 8 pairs (w1[16], b1)
    int kp = rel >> 5, m = rel & 31;
    a = w1[2*kp*32 + m];
    b = (2*kp+1 < 17) ? w1[(2*kp+1)*32 + m] : b1[m];
  } else if (rel < 832){                // W2p: k-pairs, row 16 = (b2, 0)
    int j = rel - 288, kp = j >> 5, m = j & 31;
    if (kp < 16){ a = w2[2*kp*32 + m]; b = w2[(2*kp+1)*32 + m]; }
    else        { a = b2[m];           b = 0.f; }
  } else if (pair < 3){                 // W3p34: c-pairs, rows 32=b3,33=0
    int j = rel - 832, r = j >> 5, cp = j & 31;
    if      (r < 32){ a = w3[r*64 + 2*cp]; b = w3[r*64 + 2*cp + 1]; }
    else if (r ==32){ a = b3[2*cp];        b = b3[2*cp + 1]; }
    else            { a = 0.f;             b = 0.f; }
  } else {                              // W3p17: m-pairs, mp16 = (b3, 0)
    int j = rel - 832, mp = j / 192, c = j % 192;
    if (mp < 16){ a = w3[2*mp*192 + c]; b = w3[(2*mp+1)*192 + c]; }
    else        { a = b3[c];            b = 0.f; }
  }
  ws[t] = pkh(a, b);
}

// radial MLP: xp in A[0..8], hp (h1 then h2) in A[9..24], A[25]=(1,0) const
// W is the GLOBAL ws buffer; pb is a global u32 base (wave-uniform -> s_load)
__device__ __forceinline__ void mlp(const u32* __restrict__ W, int pb, u32* __restrict__ A)
{
  float g[32];
  #pragma unroll
  for (int m = 0; m < 32; ++m) g[m] = 0.f;
  #pragma unroll 3
  for (int kp = 0; kp < 9; ++kp){
    v2h x = asvh(A[kp]);
    const uint4* __restrict__ r4 = (const uint4*)(W + pb + kp*32);
    #pragma unroll
    for (int j = 0; j < 8; ++j){
      uint4 w = r4[j];                               // s_load_dwordx4 (uniform)
      g[4*j+0] = FDOT2(asvh(w.x), x, g[4*j+0]);
      g[4*j+1] = FDOT2(asvh(w.y), x, g[4*j+1]);
      g[4*j+2] = FDOT2(asvh(w.z), x, g[4*j+2]);
      g[4*j+3] = FDOT2(asvh(w.w), x, g[4*j+3]);
    }
  }
  #pragma unroll
  for (int j = 0; j < 16; ++j)
    A[9+j] = pkh(fmaxf(g[2*j], 0.f), fmaxf(g[2*j+1], 0.f));
  float g2[32];
  #pragma unroll
  for (int m = 0; m < 32; ++m) g2[m] = 0.f;
  #pragma unroll 3
  for (int kp = 0; kp < 17; ++kp){                   // kp=16 reads A[25]=(1,0) -> +b2
    v2h x = asvh(A[9+kp]);
    const uint4* __restrict__ r4 = (const uint4*)(W + pb + 288 + kp*32);
    #pragma unroll
    for (int j = 0; j < 8; ++j){
      uint4 w = r4[j];
      g2[4*j+0] = FDOT2(asvh(w.x), x, g2[4*j+0]);
      g2[4*j+1] = FDOT2(asvh(w.y), x, g2[4*j+1]);
      g2[4*j+2] = FDOT2(asvh(w.z), x, g2[4*j+2]);
      g2[4*j+3] = FDOT2(asvh(w.w), x, g2[4*j+3]);
    }
  }
  #pragma unroll
  for (int j = 0; j < 16; ++j)
    A[9+j] = pkh(fmaxf(g2[2*j], 0.f), fmaxf(g2[2*j+1], 0.f));
}

// layer3, 64 cols (c-paired): acc[o] = sum_rows h_r * (w3row . v), bias via rows 32/33
__device__ __forceinline__ void l3a(const u32* __restrict__ W, int wb,
                                    const u32* __restrict__ A,
                                    const u32 (&vp)[4], float (&acc)[8])
{
  #pragma unroll
  for (int o = 0; o < 8; ++o) acc[o] = 0.f;
  #pragma unroll 2
  for (int mp = 0; mp < 17; ++mp){
    v2h hp = asvh(A[9+mp]);
    float h0 = (float)hp[0], h1 = (float)hp[1];
    const uint4* __restrict__ rA = (const uint4*)(W + wb + (2*mp)*32);
    const uint4* __restrict__ rB = rA + 8;
    #pragma unroll
    for (int o = 0; o < 8; ++o){
      uint4 wa = rA[o];                              // s_load (uniform)
      uint4 wb2 = rB[o];
      float tA = 0.f, tB = 0.f;
      tA = FDOT2(asvh(wa.x), asvh(vp[0]), tA);
      tA = FDOT2(asvh(wa.y), asvh(vp[1]), tA);
      tA = FDOT2(asvh(wa.z), asvh(vp[2]), tA);
      tA = FDOT2(asvh(wa.w), asvh(vp[3]), tA);
      tB = FDOT2(asvh(wb2.x), asvh(vp[0]), tB);
      tB = FDOT2(asvh(wb2.y), asvh(vp[1]), tB);
      tB = FDOT2(asvh(wb2.z), asvh(vp[2]), tB);
      tB = FDOT2(asvh(wb2.w), asvh(vp[3]), tB);
      acc[o] = fmaf(h0, tA, fmaf(h1, tB, acc[o]));
    }
  }
}

__global__ __launch_bounds__(TPB, 2) void edge_kernel(
    const float* __restrict__ feat0, const float* __restrict__ feat1,
    const float* __restrict__ wE,    const float* __restrict__ radial,
    const float* __restrict__ b00,   const float* __restrict__ b01,
    const float* __restrict__ b10,   const float* __restrict__ b11,
    const int* __restrict__ src_idx, const u32* __restrict__ ws,
    float* __restrict__ out)
{
  __shared__ u32 AR[TPB * ARENA];      // per-thread arena only (27.6 KB)
  const int tid = threadIdx.x;
  const int cls = blockIdx.x & 1;
  const int e   = (blockIdx.x >> 1) * TPB + tid;
  u32* A = AR + tid * ARENA;

  // edge features -> f16 pairs in arena
  {
    const float4* wp = (const float4*)(wE + (size_t)e * 16);
    float4 a = wp[0], b = wp[1], c = wp[2], d = wp[3];
    A[0] = pkh(a.x, a.y); A[1] = pkh(a.z, a.w);
    A[2] = pkh(b.x, b.y); A[3] = pkh(b.z, b.w);
    A[4] = pkh(c.x, c.y); A[5] = pkh(c.z, c.w);
    A[6] = pkh(d.x, d.y); A[7] = pkh(d.z, d.w);
    A[8] = pkh(radial[e], 1.0f);      // pairs with (w1[16], b1) row
    A[25] = pkh(1.0f, 0.0f);          // constant (1,0) bias selector
  }
  const int idx = src_idx[e];
  // no __syncthreads needed — arena is strictly per-thread

  if (cls == 0){
    // ================= class A: pairs (0,0) + (1,0) -> out0 =================
    const float bB = b00[e];
    float B10[3];
    #pragma unroll
    for (int q = 0; q < 3; ++q) B10[q] = b10[(size_t)e*3 + q];
    u32 vp0[4], vp2[4];
    {
      const float4* f0 = (const float4*)(feat0 + (size_t)idx * 8);
      float4 a = f0[0], b = f0[1];
      vp0[0] = pkh(a.x, a.y); vp0[1] = pkh(a.z, a.w);
      vp0[2] = pkh(b.x, b.y); vp0[3] = pkh(b.z, b.w);
      const float4* f1 = (const float4*)(feat1 + (size_t)idx * 24);
      float s1[24];
      #pragma unroll
      for (int j = 0; j < 6; ++j){
        float4 v = f1[j];
        s1[4*j+0]=v.x; s1[4*j+1]=v.y; s1[4*j+2]=v.z; s1[4*j+3]=v.w;
      }
      float Uv[8];
      #pragma unroll
      for (int i = 0; i < 8; ++i)
        Uv[i] = fmaf(B10[0], s1[3*i+0], fmaf(B10[1], s1[3*i+1], B10[2]*s1[3*i+2]));
      #pragma unroll
      for (int j = 0; j < 4; ++j) vp2[j] = pkh(Uv[2*j], Uv[2*j+1]);
    }
    float msg0[8], acc[8];
    mlp(ws, 0, A);                       // pair (0,0)
    l3a(ws, 832, A, vp0, acc);
    #pragma unroll
    for (int o = 0; o < 8; ++o) msg0[o] = acc[o] * bB;
    mlp(ws, 1920, A);                    // pair (1,0)
    l3a(ws, 1920 + 832, A, vp2, acc);
    #pragma unroll
    for (int o = 0; o < 8; ++o) msg0[o] += acc[o];
    float* o0 = out + (size_t)e * 8;
    ((float4*)o0)[0] = make_float4(msg0[0], msg0[1], msg0[2], msg0[3]);
    ((float4*)o0)[1] = make_float4(msg0[4], msg0[5], msg0[6], msg0[7]);
  } else {
    // ================= class B: pairs (0,1) + (1,1) -> out1 =================
    float B01[3];
    #pragma unroll
    for (int q = 0; q < 3; ++q) B01[q] = b01[(size_t)e*3 + q];
    u32 vp0[4];
    float s1[24];
    {
      const float4* f0 = (const float4*)(feat0 + (size_t)idx * 8);
      float4 a = f0[0], b = f0[1];
      vp0[0] = pkh(a.x, a.y); vp0[1] = pkh(a.z, a.w);
      vp0[2] = pkh(b.x, b.y); vp0[3] = pkh(b.z, b.w);
      const float4* f1 = (const float4*)(feat1 + (size_t)idx * 24);
      #pragma unroll
      for (int j = 0; j < 6; ++j){
        float4 v = f1[j];
        s1[4*j+0]=v.x; s1[4*j+1]=v.y; s1[4*j+2]=v.z; s1[4*j+3]=v.w;
      }
    }
    float t01[8];
    mlp(ws, 3840, A);                    // pair (0,1)
    l3a(ws, 3840 + 832, A, vp0, t01);
    float Bv[27];
    const float* __restrict__ bp = b11 + (size_t)e * 27;
    #pragma unroll
    for (int j = 0; j < 27; ++j) Bv[j] = bp[j];
    mlp(ws, 5760, A);                    // pair (1,1)
    float* o1 = out + (size_t)E_TOT * 8 + (size_t)e * 24;
    #pragma unroll 1
    for (int o = 0; o < 8; ++o){         // stream 3 results per o -> no msg1[24] live
      float a24[24];
      #pragma unroll
      for (int c = 0; c < 24; ++c) a24[c] = 0.f;
      #pragma unroll 3
      for (int mp = 0; mp < 17; ++mp){   // mp16 row = (b3,0) with hp=(1,0)
        v2h hp = asvh(A[9+mp]);
        const uint4* __restrict__ seg = (const uint4*)(ws + 5760 + 832 + mp*192 + o*24);
        #pragma unroll
        for (int j4 = 0; j4 < 6; ++j4){
          uint4 w = seg[j4];             // s_load (uniform)
          a24[4*j4+0] = FDOT2(asvh(w.x), hp, a24[4*j4+0]);
          a24[4*j4+1] = FDOT2(asvh(w.y), hp, a24[4*j4+1]);
          a24[4*j4+2] = FDOT2(asvh(w.z), hp, a24[4*j4+2]);
          a24[4*j4+3] = FDOT2(asvh(w.w), hp, a24[4*j4+3]);
        }
      }
      float D[9];                        // D[q,f] = sum_i R[o,i,f]*s1[i,q]
      #pragma unroll
      for (int q = 0; q < 3; ++q){
        #pragma unroll
        for (int f = 0; f < 3; ++f){
          float t = 0.f;
          #pragma unroll
          for (int i = 0; i < 8; ++i) t = fmaf(a24[i*3+f], s1[i*3+q], t);
          D[q*3+f] = t;
        }
      }
      #pragma unroll
      for (int p = 0; p < 3; ++p){
        float t = t01[o] * B01[p];
        #pragma unroll
        for (int q = 0; q < 3; ++q){
          #pragma unroll
          for (int f = 0; f < 3; ++f)
            t = fmaf(Bv[p*9 + q*3 + f], D[q*3+f], t);
        }
        o1[o*3 + p] = t;                 // streamed store (merges in L2)
      }
    }
  }
}

extern "C" void kernel_launch(void* const* d_in, const int* in_sizes, int n_in,
                              void* d_out, int out_size, void* d_ws, size_t ws_size,
                              hipStream_t stream)
{
  const float* feat0 = (const float*)d_in[0];
  const float* feat1 = (const float*)d_in[1];
  const float* wE    = (const float*)d_in[2];
  const float* rad   = (const float*)d_in[3];
  const float* b00   = (const float*)d_in[4];
  const float* b01   = (const float*)d_in[11];
  const float* b10   = (const float*)d_in[18];
  const float* b11   = (const float*)d_in[25];
  const int* sidx    = (const int*)d_in[32];
  u32* ws            = (u32*)d_ws;

  // ws pair order: (0,0), (1,0), (0,1), (1,1)  -> d_in weight bases 5, 19, 12, 26
  const int base[4] = {5, 19, 12, 26};
  WPtrs S;
  for (int p = 0; p < 4; ++p)
    for (int k = 0; k < 6; ++k)
      S.p[p*6 + k] = (const float*)d_in[base[p] + k];

  prep_kernel<<<39, 256, 0, stream>>>(S, ws);
  edge_kernel<<<NBLK, TPB, 0, stream>>>(feat0, feat1, wE, rad, b00, b01, b10, b11,
                                        sidx, ws, (float*)d_out);
}

// Round 6
// 257.005 us; speedup vs baseline: 1.3565x; 1.1705x over previous
//
#include <hip/hip_runtime.h>

typedef unsigned int u32;
typedef _Float16 v2h __attribute__((ext_vector_type(2)));
typedef __fp16   v2fp __attribute__((ext_vector_type(2)));

#define E_TOT 160000
#define TPB   256
#define NBLK  1250        // (E/256)=625 tiles x 2 classes
#define ARENA 27          // u32/thread: xp[0..8] | hp[9..25] (17) | pad
// ws (u32, f16-pairs): [p(0,0):0..1920) [p(1,0):1920..3840) [p(0,1):3840..5760) [p(1,1):5760..9856)
// per p<3 pair: W1p[9][32]@+0 | W2p[17][32]@+288 | W3p[34 rows][32 cp]@+832   (rows 32=b3,33=0)
// p3 pair:      W1p@+0 | W2p@+288 | W3p[17 mp][192 c]@+832                     (mp16=(b3,0))
// Weights read DIRECTLY from global ws with wave-uniform addresses -> s_load
// into SGPRs (one fetch per wave, scalar pipe); v_dot2 takes SGPR src0.
// R6: EXACT R1 structure (best measured: 130.5us). Single change:
// amdgpu_waves_per_eu(4,4) pins the allocator's occupancy target to 4 waves/EU
// (VGPR budget 128). Without it, the LDS-derived 5-wave target made the
// allocator squeeze to 56-84 VGPR and spill ~320B/thread of class-B state
// (Bv/s1/t01/a24) -> the +25-30MB dirty WRITE drain seen in R1/R3/R5.
// Unrolls stay at 1 (R5 lesson: unroll-3 weight sweeps = 96 SGPRs live = SGPR thrash).

#if __has_builtin(__builtin_amdgcn_fdot2)
__device__ __forceinline__ float FDOT2(v2h a, v2h b, float c){
  return __builtin_amdgcn_fdot2(a, b, c, false);
}
#else
__device__ __forceinline__ float FDOT2(v2h a, v2h b, float c){
  return fmaf((float)a[0], (float)b[0], fmaf((float)a[1], (float)b[1], c));
}
#endif

__device__ __forceinline__ u32 pkh(float a, float b){
  union { v2fp h; u32 x; } u;
  u.h = __builtin_amdgcn_cvt_pkrtz(a, b);
  return u.x;
}
__device__ __forceinline__ v2h asvh(u32 x){
  union { u32 x; v2h h; } u; u.x = x; return u.h;
}

struct WPtrs { const float* p[24]; };  // pair order (0,0),(1,0),(0,1),(1,1) x {w1,b1,w2,b2,w3,b3}

__global__ __launch_bounds__(256) void prep_kernel(WPtrs S, u32* __restrict__ ws)
{
  const int t = blockIdx.x * 256 + threadIdx.x;
  if (t >= 9856) return;
  int pair, rel;
  if (t < 5760){ pair = t / 1920; rel = t % 1920; }
  else         { pair = 3;        rel = t - 5760; }
  const float* __restrict__ w1 = S.p[pair*6+0];
  const float* __restrict__ b1 = S.p[pair*6+1];
  const float* __restrict__ w2 = S.p[pair*6+2];
  const float* __restrict__ b2 = S.p[pair*6+3];
  const float* __restrict__ w3 = S.p[pair*6+4];
  const float* __restrict__ b3 = S.p[pair*6+5];
  float a, b;
  if (rel < 288){                       // W1p: k-pairs, row 8 pairs (w1[16], b1)
    int kp = rel >> 5, m = rel & 31;
    a = w1[2*kp*32 + m];
    b = (2*kp+1 < 17) ? w1[(2*kp+1)*32 + m] : b1[m];
  } else if (rel < 832){                // W2p: k-pairs, row 16 = (b2, 0)
    int j = rel - 288, kp = j >> 5, m = j & 31;
    if (kp < 16){ a = w2[2*kp*32 + m]; b = w2[(2*kp+1)*32 + m]; }
    else        { a = b2[m];           b = 0.f; }
  } else if (pair < 3){                 // W3p34: c-pairs, rows 32=b3,33=0
    int j = rel - 832, r = j >> 5, cp = j & 31;
    if      (r < 32){ a = w3[r*64 + 2*cp]; b = w3[r*64 + 2*cp + 1]; }
    else if (r ==32){ a = b3[2*cp];        b = b3[2*cp + 1]; }
    else            { a = 0.f;             b = 0.f; }
  } else {                              // W3p17: m-pairs, mp16 = (b3, 0)
    int j = rel - 832, mp = j / 192, c = j % 192;
    if (mp < 16){ a = w3[2*mp*192 + c]; b = w3[(2*mp+1)*192 + c]; }
    else        { a = b3[c];            b = 0.f; }
  }
  ws[t] = pkh(a, b);
}

// radial MLP: xp in A[0..8], hp (h1 then h2) in A[9..24], A[25]=(1,0) const
// W is the GLOBAL ws buffer; pb is a global u32 base (wave-uniform -> s_load)
__device__ __forceinline__ void mlp(const u32* __restrict__ W, int pb, u32* __restrict__ A)
{
  float g[32];
  #pragma unroll
  for (int m = 0; m < 32; ++m) g[m] = 0.f;
  #pragma unroll 1
  for (int kp = 0; kp < 9; ++kp){
    v2h x = asvh(A[kp]);
    const uint4* __restrict__ r4 = (const uint4*)(W + pb + kp*32);
    #pragma unroll
    for (int j = 0; j < 8; ++j){
      uint4 w = r4[j];                               // s_load_dwordx4 (uniform)
      g[4*j+0] = FDOT2(asvh(w.x), x, g[4*j+0]);
      g[4*j+1] = FDOT2(asvh(w.y), x, g[4*j+1]);
      g[4*j+2] = FDOT2(asvh(w.z), x, g[4*j+2]);
      g[4*j+3] = FDOT2(asvh(w.w), x, g[4*j+3]);
    }
  }
  #pragma unroll
  for (int j = 0; j < 16; ++j)
    A[9+j] = pkh(fmaxf(g[2*j], 0.f), fmaxf(g[2*j+1], 0.f));
  float g2[32];
  #pragma unroll
  for (int m = 0; m < 32; ++m) g2[m] = 0.f;
  #pragma unroll 1
  for (int kp = 0; kp < 17; ++kp){                   // kp=16 reads A[25]=(1,0) -> +b2
    v2h x = asvh(A[9+kp]);
    const uint4* __restrict__ r4 = (const uint4*)(W + pb + 288 + kp*32);
    #pragma unroll
    for (int j = 0; j < 8; ++j){
      uint4 w = r4[j];
      g2[4*j+0] = FDOT2(asvh(w.x), x, g2[4*j+0]);
      g2[4*j+1] = FDOT2(asvh(w.y), x, g2[4*j+1]);
      g2[4*j+2] = FDOT2(asvh(w.z), x, g2[4*j+2]);
      g2[4*j+3] = FDOT2(asvh(w.w), x, g2[4*j+3]);
    }
  }
  #pragma unroll
  for (int j = 0; j < 16; ++j)
    A[9+j] = pkh(fmaxf(g2[2*j], 0.f), fmaxf(g2[2*j+1], 0.f));
}

// layer3, 64 cols (c-paired): acc[o] = sum_rows h_r * (w3row . v), bias via rows 32/33
__device__ __forceinline__ void l3a(const u32* __restrict__ W, int wb,
                                    const u32* __restrict__ A,
                                    const u32 (&vp)[4], float (&acc)[8])
{
  #pragma unroll
  for (int o = 0; o < 8; ++o) acc[o] = 0.f;
  #pragma unroll 1
  for (int mp = 0; mp < 17; ++mp){
    v2h hp = asvh(A[9+mp]);
    float h0 = (float)hp[0], h1 = (float)hp[1];
    const uint4* __restrict__ rA = (const uint4*)(W + wb + (2*mp)*32);
    const uint4* __restrict__ rB = rA + 8;
    #pragma unroll
    for (int o = 0; o < 8; ++o){
      uint4 wa = rA[o];                              // s_load (uniform)
      uint4 wb2 = rB[o];
      float tA = 0.f, tB = 0.f;
      tA = FDOT2(asvh(wa.x), asvh(vp[0]), tA);
      tA = FDOT2(asvh(wa.y), asvh(vp[1]), tA);
      tA = FDOT2(asvh(wa.z), asvh(vp[2]), tA);
      tA = FDOT2(asvh(wa.w), asvh(vp[3]), tA);
      tB = FDOT2(asvh(wb2.x), asvh(vp[0]), tB);
      tB = FDOT2(asvh(wb2.y), asvh(vp[1]), tB);
      tB = FDOT2(asvh(wb2.z), asvh(vp[2]), tB);
      tB = FDOT2(asvh(wb2.w), asvh(vp[3]), tB);
      acc[o] = fmaf(h0, tA, fmaf(h1, tB, acc[o]));
    }
  }
}

__global__ __launch_bounds__(TPB)
__attribute__((amdgpu_waves_per_eu(4, 4)))
void edge_kernel(
    const float* __restrict__ feat0, const float* __restrict__ feat1,
    const float* __restrict__ wE,    const float* __restrict__ radial,
    const float* __restrict__ b00,   const float* __restrict__ b01,
    const float* __restrict__ b10,   const float* __restrict__ b11,
    const int* __restrict__ src_idx, const u32* __restrict__ ws,
    float* __restrict__ out)
{
  __shared__ u32 AR[TPB * ARENA];      // per-thread arena only (27.6 KB)
  const int tid = threadIdx.x;
  const int cls = blockIdx.x & 1;
  const int e   = (blockIdx.x >> 1) * TPB + tid;
  u32* A = AR + tid * ARENA;

  // edge features -> f16 pairs in arena
  {
    const float4* wp = (const float4*)(wE + (size_t)e * 16);
    float4 a = wp[0], b = wp[1], c = wp[2], d = wp[3];
    A[0] = pkh(a.x, a.y); A[1] = pkh(a.z, a.w);
    A[2] = pkh(b.x, b.y); A[3] = pkh(b.z, b.w);
    A[4] = pkh(c.x, c.y); A[5] = pkh(c.z, c.w);
    A[6] = pkh(d.x, d.y); A[7] = pkh(d.z, d.w);
    A[8] = pkh(radial[e], 1.0f);      // pairs with (w1[16], b1) row
    A[25] = pkh(1.0f, 0.0f);          // constant (1,0) bias selector
  }
  const int idx = src_idx[e];
  // no __syncthreads needed — arena is strictly per-thread

  if (cls == 0){
    // ================= class A: pairs (0,0) + (1,0) -> out0 =================
    const float bB = b00[e];
    float B10[3];
    #pragma unroll
    for (int q = 0; q < 3; ++q) B10[q] = b10[(size_t)e*3 + q];
    u32 vp0[4], vp2[4];
    {
      const float4* f0 = (const float4*)(feat0 + (size_t)idx * 8);
      float4 a = f0[0], b = f0[1];
      vp0[0] = pkh(a.x, a.y); vp0[1] = pkh(a.z, a.w);
      vp0[2] = pkh(b.x, b.y); vp0[3] = pkh(b.z, b.w);
      const float4* f1 = (const float4*)(feat1 + (size_t)idx * 24);
      float s1[24];
      #pragma unroll
      for (int j = 0; j < 6; ++j){
        float4 v = f1[j];
        s1[4*j+0]=v.x; s1[4*j+1]=v.y; s1[4*j+2]=v.z; s1[4*j+3]=v.w;
      }
      float Uv[8];
      #pragma unroll
      for (int i = 0; i < 8; ++i)
        Uv[i] = fmaf(B10[0], s1[3*i+0], fmaf(B10[1], s1[3*i+1], B10[2]*s1[3*i+2]));
      #pragma unroll
      for (int j = 0; j < 4; ++j) vp2[j] = pkh(Uv[2*j], Uv[2*j+1]);
    }
    float msg0[8], acc[8];
    mlp(ws, 0, A);                       // pair (0,0)
    l3a(ws, 832, A, vp0, acc);
    #pragma unroll
    for (int o = 0; o < 8; ++o) msg0[o] = acc[o] * bB;
    mlp(ws, 1920, A);                    // pair (1,0)
    l3a(ws, 1920 + 832, A, vp2, acc);
    #pragma unroll
    for (int o = 0; o < 8; ++o) msg0[o] += acc[o];
    float* o0 = out + (size_t)e * 8;
    ((float4*)o0)[0] = make_float4(msg0[0], msg0[1], msg0[2], msg0[3]);
    ((float4*)o0)[1] = make_float4(msg0[4], msg0[5], msg0[6], msg0[7]);
  } else {
    // ================= class B: pairs (0,1) + (1,1) -> out1 =================
    float B01[3];
    #pragma unroll
    for (int q = 0; q < 3; ++q) B01[q] = b01[(size_t)e*3 + q];
    u32 vp0[4];
    float s1[24];
    {
      const float4* f0 = (const float4*)(feat0 + (size_t)idx * 8);
      float4 a = f0[0], b = f0[1];
      vp0[0] = pkh(a.x, a.y); vp0[1] = pkh(a.z, a.w);
      vp0[2] = pkh(b.x, b.y); vp0[3] = pkh(b.z, b.w);
      const float4* f1 = (const float4*)(feat1 + (size_t)idx * 24);
      #pragma unroll
      for (int j = 0; j < 6; ++j){
        float4 v = f1[j];
        s1[4*j+0]=v.x; s1[4*j+1]=v.y; s1[4*j+2]=v.z; s1[4*j+3]=v.w;
      }
    }
    float t01[8];
    mlp(ws, 3840, A);                    // pair (0,1)
    l3a(ws, 3840 + 832, A, vp0, t01);
    float Bv[27];
    const float* __restrict__ bp = b11 + (size_t)e * 27;
    #pragma unroll
    for (int j = 0; j < 27; ++j) Bv[j] = bp[j];
    mlp(ws, 5760, A);                    // pair (1,1)
    float* o1 = out + (size_t)E_TOT * 8 + (size_t)e * 24;
    #pragma unroll
    for (int o = 0; o < 8; ++o){         // stream 3 results per o -> no msg1[24] live
      float a24[24];
      #pragma unroll
      for (int c = 0; c < 24; ++c) a24[c] = 0.f;
      #pragma unroll 1
      for (int mp = 0; mp < 17; ++mp){   // mp16 row = (b3,0) with hp=(1,0)
        v2h hp = asvh(A[9+mp]);
        const uint4* __restrict__ seg = (const uint4*)(ws + 5760 + 832 + mp*192 + o*24);
        #pragma unroll
        for (int j4 = 0; j4 < 6; ++j4){
          uint4 w = seg[j4];             // s_load (uniform)
          a24[4*j4+0] = FDOT2(asvh(w.x), hp, a24[4*j4+0]);
          a24[4*j4+1] = FDOT2(asvh(w.y), hp, a24[4*j4+1]);
          a24[4*j4+2] = FDOT2(asvh(w.z), hp, a24[4*j4+2]);
          a24[4*j4+3] = FDOT2(asvh(w.w), hp, a24[4*j4+3]);
        }
      }
      float D[9];                        // D[q,f] = sum_i R[o,i,f]*s1[i,q]
      #pragma unroll
      for (int q = 0; q < 3; ++q){
        #pragma unroll
        for (int f = 0; f < 3; ++f){
          float t = 0.f;
          #pragma unroll
          for (int i = 0; i < 8; ++i) t = fmaf(a24[i*3+f], s1[i*3+q], t);
          D[q*3+f] = t;
        }
      }
      #pragma unroll
      for (int p = 0; p < 3; ++p){
        float t = t01[o] * B01[p];
        #pragma unroll
        for (int q = 0; q < 3; ++q){
          #pragma unroll
          for (int f = 0; f < 3; ++f)
            t = fmaf(Bv[p*9 + q*3 + f], D[q*3+f], t);
        }
        o1[o*3 + p] = t;                 // streamed store (merges in L2)
      }
    }
  }
}

extern "C" void kernel_launch(void* const* d_in, const int* in_sizes, int n_in,
                              void* d_out, int out_size, void* d_ws, size_t ws_size,
                              hipStream_t stream)
{
  const float* feat0 = (const float*)d_in[0];
  const float* feat1 = (const float*)d_in[1];
  const float* wE    = (const float*)d_in[2];
  const float* rad   = (const float*)d_in[3];
  const float* b00   = (const float*)d_in[4];
  const float* b01   = (const float*)d_in[11];
  const float* b10   = (const float*)d_in[18];
  const float* b11   = (const float*)d_in[25];
  const int* sidx    = (const int*)d_in[32];
  u32* ws            = (u32*)d_ws;

  // ws pair order: (0,0), (1,0), (0,1), (1,1)  -> d_in weight bases 5, 19, 12, 26
  const int base[4] = {5, 19, 12, 26};
  WPtrs S;
  for (int p = 0; p < 4; ++p)
    for (int k = 0; k < 6; ++k)
      S.p[p*6 + k] = (const float*)d_in[base[p] + k];

  prep_kernel<<<39, 256, 0, stream>>>(S, ws);
  edge_kernel<<<NBLK, TPB, 0, stream>>>(feat0, feat1, wE, rad, b00, b01, b10, b11,
                                        sidx, ws, (float*)d_out);
}